// Round 16
// baseline (597.571 us; speedup 1.0000x reference)
//
#include <hip/hip_runtime.h>
#include <hip/hip_cooperative_groups.h>
#include <math.h>

namespace cg = cooperative_groups;

#define N_NODES 50000
#define N_EDGES 800000
#define NGRAPH  64
#define SCAN_BLOCKS ((N_NODES + 255) / 256)   // 196
#define LROW 136   // LDS x-tile row stride (shorts): 272B, 16B-aligned rows
#define COOP_BLOCKS 256

typedef __bf16 bf16x8 __attribute__((ext_vector_type(8)));
typedef float  f32x4  __attribute__((ext_vector_type(4)));
typedef float  f32x2  __attribute__((ext_vector_type(2)));

__device__ __forceinline__ unsigned short f2bf(float f) {
    unsigned u = __float_as_uint(f);
    u += 0x7fff + ((u >> 16) & 1);          // round-to-nearest-even
    return (unsigned short)(u >> 16);
}
__device__ __forceinline__ float bf2f(unsigned short u) {
    return __uint_as_float((unsigned)u << 16);
}

// ---------------------------------------------------------------------------
// Cooperative front-end: CSR build + weight prep + pool init, ONE launch.
// Phases separated by grid.sync() (device-scope fence):
//  1: zero counts/psum/pmax, pcnt via binary search (gi sorted)
//  2: degree atomics (4 edges/thread) + weight prep (independent, overlapped)
//  3: per-segment count sums -> bsum
//  4: scan bsum (block 0)
//  5: per-segment scan -> offs, cursor
//  6: scatter edges into CSR
// ---------------------------------------------------------------------------
__global__ __launch_bounds__(256) void coop_prep_kernel(
    const int* __restrict__ ei, const int* __restrict__ gi,
    const float* __restrict__ Wq, const float* __restrict__ Wk, const float* __restrict__ Wv,
    const float* __restrict__ Wsk, const float* __restrict__ Wt,
    const float* __restrict__ bs, const float* __restrict__ bt,
    unsigned short* __restrict__ outq, unsigned short* __restrict__ outf,
    float* __restrict__ bc,
    int* __restrict__ counts, int* __restrict__ offs, int* __restrict__ cursor,
    int* __restrict__ csr, int* __restrict__ bsum, int* __restrict__ boff,
    float* __restrict__ psum, unsigned* __restrict__ pmax, int* __restrict__ pcnt) {
    cg::grid_group grid = cg::this_grid();
    int tid = threadIdx.x;
    int gid = blockIdx.x * 256 + tid;
    int gsz = gridDim.x * 256;
    int lane = tid & 63, wid = tid >> 6;
    __shared__ int ws[4];

    // ---- phase 1: zeroing + pcnt ----
    for (int i = gid; i < N_NODES; i += gsz) counts[i] = 0;
    for (int i = gid; i < NGRAPH * 128; i += gsz) { psum[i] = 0.f; pmax[i] = 0u; }
    if (gid < NGRAPH) {
        auto lb = [&](int target) {
            int lo = 0, hi = N_NODES;
            while (lo < hi) {
                int mid = (lo + hi) >> 1;
                if (gi[mid] < target) lo = mid + 1;
                else hi = mid;
            }
            return lo;
        };
        pcnt[gid] = lb(gid + 1) - lb(gid);
    }
    grid.sync();

    // ---- phase 2: degree atomics + weight prep ----
    for (int e4 = gid * 4; e4 < N_EDGES; e4 += gsz * 4) {
        int4 d = *(const int4*)(ei + N_EDGES + e4);
        atomicAdd(&counts[d.x], 1);
        atomicAdd(&counts[d.y], 1);
        atomicAdd(&counts[d.z], 1);
        atomicAdd(&counts[d.w], 1);
    }
    for (int idx = gid; idx < 295168; idx += gsz) {
        if (idx < 196608) {
            int j = idx & 7, ln = (idx >> 3) & 63, ct = (idx >> 9) & 15, ks = (idx >> 13) & 3;
            int m3 = idx >> 15;
            int l = m3 / 3, m = m3 % 3;
            int k = ks * 32 + ((ln >> 4) * 8) + j;
            int n = ct * 16 + (ln & 15);
            const float* W = (m == 0) ? Wq : (m == 1) ? Wk : Wv;
            outq[idx] = f2bf(W[(size_t)l * 32768 + k * 256 + n]);
        } else if (idx < 294912) {
            int r = idx - 196608;
            int l = r / 49152, rr = r % 49152;
            int j = rr & 7, ln = (rr >> 3) & 63;
            int rest = rr >> 9;
            int ct = rest & 7, ks = rest >> 3;
            int k = ks * 32 + ((ln >> 4) * 8) + j;
            int n = ct * 16 + (ln & 15);
            float v;
            if (k < 256) {
                v = Wt[(size_t)l * 32768 + k * 128 + n];
            } else {
                const float* wsp = Wsk + (size_t)l * 32768 + (size_t)(k - 256) * 256;
                const float* wtp = Wt + (size_t)l * 32768;
                float s = 0.f;
                for (int kk = 0; kk < 256; kk++) s = fmaf(wsp[kk], wtp[kk * 128 + n], s);
                v = s;
            }
            outf[r] = f2bf(v);
        } else {
            int t = idx - 294912;
            int l = t >> 7, jj = t & 127;
            const float* wtp = Wt + (size_t)l * 32768;
            float s = bt[l * 128 + jj];
            for (int kk = 0; kk < 256; kk++) s = fmaf(bs[l * 256 + kk], wtp[kk * 128 + jj], s);
            bc[t] = s;
        }
    }
    grid.sync();

    // ---- phase 3: segment sums ----
    for (int vb = blockIdx.x; vb < SCAN_BLOCKS; vb += gridDim.x) {
        int i = vb * 256 + tid;
        int v = (i < N_NODES) ? counts[i] : 0;
        #pragma unroll
        for (int o = 32; o >= 1; o >>= 1) v += __shfl_xor(v, o);
        if (lane == 0) ws[wid] = v;
        __syncthreads();
        if (tid == 0) bsum[vb] = ws[0] + ws[1] + ws[2] + ws[3];
        __syncthreads();
    }
    grid.sync();

    // ---- phase 4: scan bsum (block 0) ----
    if (blockIdx.x == 0) {
        int v = (tid < SCAN_BLOCKS) ? bsum[tid] : 0;
        int incl = v;
        #pragma unroll
        for (int o = 1; o < 64; o <<= 1) {
            int tv = __shfl_up(incl, o);
            if (lane >= o) incl += tv;
        }
        if (lane == 63) ws[wid] = incl;
        __syncthreads();
        int add = 0;
        for (int w = 0; w < wid; w++) add += ws[w];
        if (tid < SCAN_BLOCKS) boff[tid] = add + incl - v;   // exclusive
    }
    grid.sync();

    // ---- phase 5: per-segment scan -> offs, cursor ----
    for (int vb = blockIdx.x; vb < SCAN_BLOCKS; vb += gridDim.x) {
        int i = vb * 256 + tid;
        int v = (i < N_NODES) ? counts[i] : 0;
        int incl = v;
        #pragma unroll
        for (int o = 1; o < 64; o <<= 1) {
            int tv = __shfl_up(incl, o);
            if (lane >= o) incl += tv;
        }
        if (lane == 63) ws[wid] = incl;
        __syncthreads();
        int add = boff[vb];
        for (int w = 0; w < wid; w++) add += ws[w];
        if (i < N_NODES) {
            offs[i + 1] = add + incl;
            cursor[i]   = add + incl - v;
        }
        if (i == 0) offs[0] = 0;
        __syncthreads();
    }
    grid.sync();

    // ---- phase 6: scatter ----
    for (int e4 = gid * 4; e4 < N_EDGES; e4 += gsz * 4) {
        int4 s = *(const int4*)(ei + e4);
        int4 d = *(const int4*)(ei + N_EDGES + e4);
        csr[atomicAdd(&cursor[d.x], 1)] = s.x;
        csr[atomicAdd(&cursor[d.y], 1)] = s.y;
        csr[atomicAdd(&cursor[d.z], 1)] = s.z;
        csr[atomicAdd(&cursor[d.w], 1)] = s.w;
    }
}

// ---------------------------------------------------------------------------
// Cooperative proj stage (R13 structure): 256-thread block, wave w owns 32
// rows whose bf16 x sit in its LDS tile slice. Weights streamed through a
// double-buffered 8 KB LDS chunk shared by all 4 waves.
// q -> bf16; k,v -> fp8 e4m3 into kv8 rows (uint 2c = k, 2c+1 = v).
// ---------------------------------------------------------------------------
__device__ __forceinline__ void proj_stream(
    const unsigned short* Tw, unsigned short* WB,
    const unsigned short* __restrict__ Wp,
    const float* __restrict__ b0, const float* __restrict__ b1, const float* __restrict__ b2,
    unsigned short* __restrict__ oq, unsigned* __restrict__ kv8,
    int rbase, int tid) {
    int lane = tid & 63, quad = lane >> 4, lr = lane & 15;
    int n0 = rbase + lr, n1 = rbase + 16 + lr;
    const float* bias[3] = {b0, b1, b2};

    bf16x8 pa0[4], pa1[4];
    #pragma unroll
    for (int ks = 0; ks < 4; ks++) {
        pa0[ks] = *(const bf16x8*)(Tw + lr * LROW + ks * 32 + quad * 8);
        pa1[ks] = *(const bf16x8*)(Tw + (16 + lr) * LROW + ks * 32 + quad * 8);
    }

    int f0 = tid, f1 = tid + 256;
    int ks0 = f0 >> 7, c20 = (f0 >> 6) & 1, ln0 = f0 & 63;
    int ks1 = f1 >> 7, c21 = (f1 >> 6) & 1, ln1 = f1 & 63;
    auto wload = [&](int c, uint4& r0, uint4& r1) {
        int mm = c >> 3, cp = c & 7;
        const unsigned short* base = Wp + mm * 32768;
        r0 = *(const uint4*)(base + (size_t)((ks0 * 16 + cp * 2 + c20) * 64 + ln0) * 8);
        r1 = *(const uint4*)(base + (size_t)((ks1 * 16 + cp * 2 + c21) * 64 + ln1) * 8);
    };

    auto epi = [&](int mm, int ct, const f32x4& e0, const f32x4& e1) {
        int ob = ct * 16 + quad * 4;
        float4 bb = *(const float4*)&bias[mm][ob];
        float v00 = e0[0] + bb.x, v01 = e0[1] + bb.y, v02 = e0[2] + bb.z, v03 = e0[3] + bb.w;
        float v10 = e1[0] + bb.x, v11 = e1[1] + bb.y, v12 = e1[2] + bb.z, v13 = e1[3] + bb.w;
        if (mm == 0) {
            ushort4 s0, s1;
            s0.x = f2bf(v00); s0.y = f2bf(v01); s0.z = f2bf(v02); s0.w = f2bf(v03);
            s1.x = f2bf(v10); s1.y = f2bf(v11); s1.z = f2bf(v12); s1.w = f2bf(v13);
            if (n0 < N_NODES) *(ushort4*)(oq + (size_t)n0 * 256 + ob) = s0;
            if (n1 < N_NODES) *(ushort4*)(oq + (size_t)n1 * 256 + ob) = s1;
        } else {
            int u0 = __builtin_amdgcn_cvt_pk_fp8_f32(v00, v01, 0, false);
            u0 = __builtin_amdgcn_cvt_pk_fp8_f32(v02, v03, u0, true);
            int u1 = __builtin_amdgcn_cvt_pk_fp8_f32(v10, v11, 0, false);
            u1 = __builtin_amdgcn_cvt_pk_fp8_f32(v12, v13, u1, true);
            int kvo = (ob >> 2) * 2 + (mm - 1);
            if (n0 < N_NODES) kv8[(size_t)n0 * 128 + kvo] = (unsigned)u0;
            if (n1 < N_NODES) kv8[(size_t)n1 * 128 + kvo] = (unsigned)u1;
        }
    };

    uint4 wr0, wr1;
    wload(0, wr0, wr1);
    ((uint4*)WB)[tid] = wr0;
    ((uint4*)WB)[tid + 256] = wr1;
    __syncthreads();

    for (int c = 0; c < 24; c++) {
        if (c < 23) wload(c + 1, wr0, wr1);
        const unsigned short* wb = WB + (c & 1) * 4096;
        f32x4 d00 = {0.f, 0.f, 0.f, 0.f}, d01 = {0.f, 0.f, 0.f, 0.f};
        f32x4 d10 = {0.f, 0.f, 0.f, 0.f}, d11 = {0.f, 0.f, 0.f, 0.f};
        #pragma unroll
        for (int ks = 0; ks < 4; ks++) {
            bf16x8 wf0 = *(const bf16x8*)(wb + ((ks * 2 + 0) * 64 + lane) * 8);
            bf16x8 wf1 = *(const bf16x8*)(wb + ((ks * 2 + 1) * 64 + lane) * 8);
            d00 = __builtin_amdgcn_mfma_f32_16x16x32_bf16(wf0, pa0[ks], d00, 0, 0, 0);
            d01 = __builtin_amdgcn_mfma_f32_16x16x32_bf16(wf0, pa1[ks], d01, 0, 0, 0);
            d10 = __builtin_amdgcn_mfma_f32_16x16x32_bf16(wf1, pa0[ks], d10, 0, 0, 0);
            d11 = __builtin_amdgcn_mfma_f32_16x16x32_bf16(wf1, pa1[ks], d11, 0, 0, 0);
        }
        int mm = c >> 3, ct0 = (c & 7) * 2;
        epi(mm, ct0, d00, d01);
        epi(mm, ct0 + 1, d10, d11);
        if (c < 23) {
            ((uint4*)(WB + ((c + 1) & 1) * 4096))[tid] = wr0;
            ((uint4*)(WB + ((c + 1) & 1) * 4096))[tid + 256] = wr1;
        }
        __syncthreads();
    }
}

// ---------------------------------------------------------------------------
// Layer-0 front (coop 128-row blocks): fp32 x -> bf16 xb (global) + LDS tile,
// then streamed qkv projection.
// ---------------------------------------------------------------------------
__global__ __launch_bounds__(256) void fproj_kernel(
    const float* __restrict__ xf, unsigned short* __restrict__ xb,
    const unsigned short* __restrict__ Wp,
    const float* __restrict__ b0, const float* __restrict__ b1, const float* __restrict__ b2,
    unsigned short* __restrict__ oq, unsigned* __restrict__ kv8) {
    __shared__ unsigned short T[128 * LROW];
    __shared__ unsigned short WB[8192];
    int tid = threadIdx.x;
    int w = tid >> 6, lane = tid & 63;
    int quad = lane >> 4, lr = lane & 15;
    int rbase = blockIdx.x * 128 + w * 32;
    unsigned short* Tw = T + w * 32 * LROW;

    #pragma unroll
    for (int s = 0; s < 2; s++) {
        int row = rbase + s * 16 + lr;
        if (row < N_NODES) {
            const float4* src = (const float4*)(xf + (size_t)row * 128 + quad * 32);
            ushort4* gdst = (ushort4*)(xb + (size_t)row * 128 + quad * 32);
            ushort4* ldst = (ushort4*)(Tw + (s * 16 + lr) * LROW + quad * 32);
            #pragma unroll
            for (int i = 0; i < 8; i++) {
                float4 v = src[i];
                ushort4 o;
                o.x = f2bf(v.x); o.y = f2bf(v.y); o.z = f2bf(v.z); o.w = f2bf(v.w);
                gdst[i] = o;
                ldst[i] = o;
            }
        }
    }
    proj_stream(Tw, WB, Wp, b0, b1, b2, oq, kv8, rbase, tid);
}

// ---------------------------------------------------------------------------
// Fused output linear (+ next layer's qkv projection when do_proj), coop
// 128-row blocks: x_next = relu([h|x] @ [Wt;Wc] + bc), weights streamed by ks
// through the LDS double buffer (12 chunks), A prefetched 1 ahead.
// ---------------------------------------------------------------------------
__global__ __launch_bounds__(256) void outproj_kernel(
    const unsigned short* __restrict__ hb, const unsigned short* __restrict__ xbin,
    const unsigned short* __restrict__ Wfp, const float* __restrict__ bc,
    unsigned short* __restrict__ xbout,
    const unsigned short* __restrict__ Wp,
    const float* __restrict__ b0, const float* __restrict__ b1, const float* __restrict__ b2,
    unsigned short* __restrict__ oq, unsigned* __restrict__ kv8, int do_proj) {
    __shared__ unsigned short T[128 * LROW];
    __shared__ unsigned short WB[8192];
    int tid = threadIdx.x;
    int w = tid >> 6, lane = tid & 63;
    int quad = lane >> 4, lr = lane & 15;
    int rbase = blockIdx.x * 128 + w * 32;
    int n0 = rbase + lr, n1 = rbase + 16 + lr;
    int n0c = min(n0, N_NODES - 1), n1c = min(n1, N_NODES - 1);
    unsigned short* Tw = T + w * 32 * LROW;

    auto load_a = [&](int ks, bf16x8& x0, bf16x8& x1) {
        if (ks < 8) {
            x0 = *(const bf16x8*)(hb + (size_t)n0c * 256 + ks * 32 + quad * 8);
            x1 = *(const bf16x8*)(hb + (size_t)n1c * 256 + ks * 32 + quad * 8);
        } else {
            x0 = *(const bf16x8*)(xbin + (size_t)n0c * 128 + (ks - 8) * 32 + quad * 8);
            x1 = *(const bf16x8*)(xbin + (size_t)n1c * 128 + (ks - 8) * 32 + quad * 8);
        }
    };

    f32x4 acc[8][2];
    #pragma unroll
    for (int ct = 0; ct < 8; ct++) {
        acc[ct][0] = (f32x4){0.f, 0.f, 0.f, 0.f};
        acc[ct][1] = (f32x4){0.f, 0.f, 0.f, 0.f};
    }

    uint4 wr0 = ((const uint4*)Wfp)[tid];
    uint4 wr1 = ((const uint4*)Wfp)[tid + 256];
    ((uint4*)WB)[tid] = wr0;
    ((uint4*)WB)[tid + 256] = wr1;
    bf16x8 a0c, a1c, a0n, a1n;
    load_a(0, a0c, a1c);
    __syncthreads();

    for (int ks = 0; ks < 12; ks++) {
        if (ks < 11) {
            wr0 = ((const uint4*)(Wfp + (size_t)(ks + 1) * 4096))[tid];
            wr1 = ((const uint4*)(Wfp + (size_t)(ks + 1) * 4096))[tid + 256];
            load_a(ks + 1, a0n, a1n);
        }
        const unsigned short* wb = WB + (ks & 1) * 4096;
        #pragma unroll
        for (int ct = 0; ct < 8; ct++) {
            bf16x8 wf = *(const bf16x8*)(wb + (ct * 64 + lane) * 8);
            acc[ct][0] = __builtin_amdgcn_mfma_f32_16x16x32_bf16(wf, a0c, acc[ct][0], 0, 0, 0);
            acc[ct][1] = __builtin_amdgcn_mfma_f32_16x16x32_bf16(wf, a1c, acc[ct][1], 0, 0, 0);
        }
        if (ks < 11) {
            ((uint4*)(WB + ((ks + 1) & 1) * 4096))[tid] = wr0;
            ((uint4*)(WB + ((ks + 1) & 1) * 4096))[tid + 256] = wr1;
            a0c = a0n;
            a1c = a1n;
        }
        __syncthreads();
    }

    #pragma unroll
    for (int ct = 0; ct < 8; ct++) {
        int ob = ct * 16 + quad * 4;
        float4 bb = *(const float4*)&bc[ob];
        ushort4 s0, s1;
        s0.x = f2bf(fmaxf(acc[ct][0][0] + bb.x, 0.f));
        s0.y = f2bf(fmaxf(acc[ct][0][1] + bb.y, 0.f));
        s0.z = f2bf(fmaxf(acc[ct][0][2] + bb.z, 0.f));
        s0.w = f2bf(fmaxf(acc[ct][0][3] + bb.w, 0.f));
        s1.x = f2bf(fmaxf(acc[ct][1][0] + bb.x, 0.f));
        s1.y = f2bf(fmaxf(acc[ct][1][1] + bb.y, 0.f));
        s1.z = f2bf(fmaxf(acc[ct][1][2] + bb.z, 0.f));
        s1.w = f2bf(fmaxf(acc[ct][1][3] + bb.w, 0.f));
        if (n0 < N_NODES) *(ushort4*)(xbout + (size_t)n0 * 128 + ob) = s0;
        if (n1 < N_NODES) *(ushort4*)(xbout + (size_t)n1 * 128 + ob) = s1;
        *(ushort4*)(Tw + lr * LROW + ob) = s0;
        *(ushort4*)(Tw + (16 + lr) * LROW + ob) = s1;
    }

    if (do_proj) {
        proj_stream(Tw, WB, Wp, b0, b1, b2, oq, kv8, rbase, tid);
    }
}

// ---------------------------------------------------------------------------
// Attention: 256-thread blocks, one dst/wave, unroll 8. Single pass, no
// max-subtraction (|logit|<~3, exp-safe; softmax shift-invariant).
// k,v both fp8 e4m3: lane reads ONE uint2 (8B) = [k-pack | v-pack] per edge.
// ---------------------------------------------------------------------------
__global__ __launch_bounds__(256) void attn_kernel(
    const unsigned short* __restrict__ q, const unsigned* __restrict__ kv8,
    const int* __restrict__ offs, const int* __restrict__ csr,
    unsigned short* __restrict__ hout) {
    const float SCALE = 0.08838834764831845f;  // 1/sqrt(128)
    int w = threadIdx.x >> 6, lane = threadIdx.x & 63;
    int n = blockIdx.x * 4 + w;                // 12500*4 = 50000 exactly
    ushort4 qu = ((const ushort4*)(q + (size_t)n * 256))[lane];
    float4 q4 = make_float4(bf2f(qu.x), bf2f(qu.y), bf2f(qu.z), bf2f(qu.w));
    int beg = offs[n], end = offs[n + 1];

    float4 acc = make_float4(0.f, 0.f, 0.f, 0.f);
    float d = 0.f;

    int j = beg;
    for (; j + 8 <= end; j += 8) {
        uint2 c[8];
        #pragma unroll
        for (int u = 0; u < 8; u++) {
            int s = csr[j + u];
            c[u] = ((const uint2*)(kv8 + (size_t)s * 128))[lane];
        }
        float p[8];
        #pragma unroll
        for (int u = 0; u < 8; u++) {
            f32x2 lo = __builtin_amdgcn_cvt_pk_f32_fp8((int)c[u].x, false);
            f32x2 hi = __builtin_amdgcn_cvt_pk_f32_fp8((int)c[u].x, true);
            p[u] = q4.x * lo.x + q4.y * lo.y + q4.z * hi.x + q4.w * hi.y;
        }
        #pragma unroll
        for (int o = 16; o >= 1; o >>= 1) {
            #pragma unroll
            for (int u = 0; u < 8; u++) p[u] += __shfl_xor(p[u], o);
        }
        #pragma unroll
        for (int u = 0; u < 8; u++) {
            float e = __expf(p[u] * SCALE);
            d += e;
            f32x2 vlo = __builtin_amdgcn_cvt_pk_f32_fp8((int)c[u].y, false);
            f32x2 vhi = __builtin_amdgcn_cvt_pk_f32_fp8((int)c[u].y, true);
            acc.x = fmaf(e, vlo.x, acc.x);
            acc.y = fmaf(e, vlo.y, acc.y);
            acc.z = fmaf(e, vhi.x, acc.z);
            acc.w = fmaf(e, vhi.y, acc.w);
        }
    }
    for (; j < end; j++) {
        int s = csr[j];
        uint2 c = ((const uint2*)(kv8 + (size_t)s * 128))[lane];
        f32x2 lo = __builtin_amdgcn_cvt_pk_f32_fp8((int)c.x, false);
        f32x2 hi = __builtin_amdgcn_cvt_pk_f32_fp8((int)c.x, true);
        float p = q4.x * lo.x + q4.y * lo.y + q4.z * hi.x + q4.w * hi.y;
        #pragma unroll
        for (int o = 16; o >= 1; o >>= 1) p += __shfl_xor(p, o);
        float e = __expf(p * SCALE);
        d += e;
        f32x2 vlo = __builtin_amdgcn_cvt_pk_f32_fp8((int)c.y, false);
        f32x2 vhi = __builtin_amdgcn_cvt_pk_f32_fp8((int)c.y, true);
        acc.x = fmaf(e, vlo.x, acc.x);
        acc.y = fmaf(e, vlo.y, acc.y);
        acc.z = fmaf(e, vhi.x, acc.z);
        acc.w = fmaf(e, vhi.y, acc.w);
    }

    float inv = 1.f / (d + 1e-16f);
    ushort4 hv;
    hv.x = f2bf(acc.x * inv);
    hv.y = f2bf(acc.y * inv);
    hv.z = f2bf(acc.z * inv);
    hv.w = f2bf(acc.w * inv);
    ((ushort4*)(hout + (size_t)n * 256))[lane] = hv;
}

// ---------------------------------------------------------------------------
// Pooling from bf16 x, ushort4-vectorized, run-compressed (gi sorted).
// relu output >= 0 => uint atomicMax order-correct, 0 is the identity.
// ---------------------------------------------------------------------------
__global__ __launch_bounds__(256) void pool_accum_kernel(
    const unsigned short* __restrict__ xb, const int* __restrict__ gi,
    float* __restrict__ psum, unsigned* __restrict__ pmax) {
    int n0 = blockIdx.x * 128;
    int c4 = (threadIdx.x & 31) * 4;        // 4 consecutive cols
    int phase = threadIdx.x >> 5;           // 0..7
    int first = n0 + phase;
    if (first >= N_NODES) return;
    float s0 = 0.f, s1 = 0.f, s2 = 0.f, s3 = 0.f;
    float m0 = 0.f, m1 = 0.f, m2 = 0.f, m3 = 0.f;
    int cur_g = gi[first];
    for (int r = phase; r < 128; r += 8) {
        int n = n0 + r;
        if (n >= N_NODES) break;
        int g = gi[n];
        if (g != cur_g) {
            float* ps = &psum[cur_g * 128 + c4];
            unsigned* pm = &pmax[cur_g * 128 + c4];
            atomicAdd(ps + 0, s0); atomicAdd(ps + 1, s1);
            atomicAdd(ps + 2, s2); atomicAdd(ps + 3, s3);
            atomicMax(pm + 0, __float_as_uint(m0)); atomicMax(pm + 1, __float_as_uint(m1));
            atomicMax(pm + 2, __float_as_uint(m2)); atomicMax(pm + 3, __float_as_uint(m3));
            s0 = s1 = s2 = s3 = 0.f;
            m0 = m1 = m2 = m3 = 0.f;
            cur_g = g;
        }
        ushort4 u = *(const ushort4*)(xb + (size_t)n * 128 + c4);
        float v0 = bf2f(u.x), v1 = bf2f(u.y), v2 = bf2f(u.z), v3 = bf2f(u.w);
        s0 += v0; s1 += v1; s2 += v2; s3 += v3;
        m0 = fmaxf(m0, v0); m1 = fmaxf(m1, v1);
        m2 = fmaxf(m2, v2); m3 = fmaxf(m3, v3);
    }
    float* ps = &psum[cur_g * 128 + c4];
    unsigned* pm = &pmax[cur_g * 128 + c4];
    atomicAdd(ps + 0, s0); atomicAdd(ps + 1, s1);
    atomicAdd(ps + 2, s2); atomicAdd(ps + 3, s3);
    atomicMax(pm + 0, __float_as_uint(m0)); atomicMax(pm + 1, __float_as_uint(m1));
    atomicMax(pm + 2, __float_as_uint(m2)); atomicMax(pm + 3, __float_as_uint(m3));
}

__global__ void pool_final_kernel(const float* __restrict__ psum, const unsigned* __restrict__ pmax,
                                  const int* __restrict__ pcnt, float* __restrict__ out) {
    int idx = blockIdx.x * 256 + threadIdx.x;
    if (idx >= NGRAPH * 384) return;
    int g = idx / 384, c = idx % 384;
    float r;
    if (c < 128)       r = __uint_as_float(pmax[g * 128 + c]);
    else if (c < 256)  r = psum[g * 128 + (c - 128)] / fmaxf((float)pcnt[g], 1.f);
    else               r = psum[g * 128 + (c - 256)];
    out[idx] = r;
}

// ---------------------------------------------------------------------------
extern "C" void kernel_launch(void* const* d_in, const int* in_sizes, int n_in,
                              void* d_out, int out_size, void* d_ws, size_t ws_size,
                              hipStream_t stream) {
    const float* x   = (const float*)d_in[0];
    const int*   ei  = (const int*)d_in[1];
    const int*   gi  = (const int*)d_in[2];
    const float* Wq  = (const float*)d_in[3];
    const float* bq  = (const float*)d_in[4];
    const float* Wk  = (const float*)d_in[5];
    const float* bk  = (const float*)d_in[6];
    const float* Wv  = (const float*)d_in[7];
    const float* bv  = (const float*)d_in[8];
    const float* Wsk = (const float*)d_in[9];
    const float* bsk = (const float*)d_in[10];
    const float* Wt  = (const float*)d_in[11];
    const float* bt  = (const float*)d_in[12];
    float* out = (float*)d_out;

    char* p = (char*)d_ws;
    auto take = [&](size_t bytes) -> char* {
        char* r = p;
        p += (bytes + 255) & ~(size_t)255;
        return r;
    };
    unsigned short* qbuf   = (unsigned short*)take((size_t)N_NODES * 256 * 2);  // q bf16
    unsigned*       kv8buf = (unsigned*)take((size_t)N_NODES * 128 * 4);        // k|v fp8 packed
    unsigned short* xb     = (unsigned short*)take((size_t)N_NODES * 128 * 2);  // x0 bf16 / final x
    unsigned short* xb2    = (unsigned short*)take((size_t)N_NODES * 128 * 2);  // x1 bf16
    unsigned short* hb     = (unsigned short*)take((size_t)N_NODES * 256 * 2);  // attn out bf16
    unsigned short* Wqkvp  = (unsigned short*)take((size_t)196608 * 2);         // packed qkv
    unsigned short* Wfp    = (unsigned short*)take((size_t)98304 * 2);          // packed [Wt;Wc]
    float*          bc     = (float*)take(2 * 128 * 4);
    int*            counts = (int*)take((size_t)N_NODES * 4);
    int*            offs   = (int*)take((size_t)(N_NODES + 1) * 4);
    int*            cursor = (int*)take((size_t)N_NODES * 4);
    int*            csr    = (int*)take((size_t)N_EDGES * 4);
    int*            bsum   = (int*)take((size_t)SCAN_BLOCKS * 4);
    int*            boff   = (int*)take((size_t)SCAN_BLOCKS * 4);
    float*          psum   = (float*)take(NGRAPH * 128 * 4);
    unsigned*       pmax   = (unsigned*)take(NGRAPH * 128 * 4);
    int*            pcnt   = (int*)take(NGRAPH * 4);

    const int GB = (N_NODES + 127) / 128;          // 391  (coop GEMM / pooling blocks)
    const int AB = (N_NODES + 3) / 4;              // 12500 (attn blocks, 4 dst/block)

    // ---- cooperative front-end: CSR + weight prep + pool init (ONE launch) ----
    {
        void* args[] = {
            (void*)&ei, (void*)&gi,
            (void*)&Wq, (void*)&Wk, (void*)&Wv, (void*)&Wsk, (void*)&Wt,
            (void*)&bsk, (void*)&bt,
            (void*)&Wqkvp, (void*)&Wfp, (void*)&bc,
            (void*)&counts, (void*)&offs, (void*)&cursor, (void*)&csr,
            (void*)&bsum, (void*)&boff,
            (void*)&psum, (void*)&pmax, (void*)&pcnt
        };
        hipLaunchCooperativeKernel((void*)coop_prep_kernel, dim3(COOP_BLOCKS), dim3(256),
                                   args, 0, stream);
    }

    // ---- layer 0 ----
    fproj_kernel<<<GB, 256, 0, stream>>>(x, xb, Wqkvp, bq, bk, bv, qbuf, kv8buf);
    attn_kernel<<<AB, 256, 0, stream>>>(qbuf, kv8buf, offs, csr, hb);
    // out(L0) fused with proj(L1)
    outproj_kernel<<<GB, 256, 0, stream>>>(hb, xb, Wfp, bc, xb2,
                                           Wqkvp + 98304, bq + 256, bk + 256, bv + 256,
                                           qbuf, kv8buf, 1);
    // ---- layer 1 ----
    attn_kernel<<<AB, 256, 0, stream>>>(qbuf, kv8buf, offs, csr, hb);
    outproj_kernel<<<GB, 256, 0, stream>>>(hb, xb2, Wfp + 49152, bc + 128, xb,
                                           Wqkvp, bq, bk, bv, qbuf, kv8buf, 0);

    // ---- pooling ----
    pool_accum_kernel<<<GB, 256, 0, stream>>>(xb, gi, psum, pmax);
    pool_final_kernel<<<(NGRAPH * 384 + 255) / 256, 256, 0, stream>>>(psum, pmax, pcnt, out);
}

// Round 17
// 449.539 us; speedup vs baseline: 1.3293x; 1.3293x over previous
//
#include <hip/hip_runtime.h>
#include <math.h>

#define N_NODES 50000
#define N_EDGES 800000
#define NGRAPH  64
#define SCAN_BLOCKS ((N_NODES + 255) / 256)   // 196
#define LROW 136   // LDS x-tile row stride (shorts): 272B, 16B-aligned rows

typedef __bf16 bf16x8 __attribute__((ext_vector_type(8)));
typedef float  f32x4  __attribute__((ext_vector_type(4)));
typedef float  f32x2  __attribute__((ext_vector_type(2)));

__device__ __forceinline__ unsigned short f2bf(float f) {
    unsigned u = __float_as_uint(f);
    u += 0x7fff + ((u >> 16) & 1);          // round-to-nearest-even
    return (unsigned short)(u >> 16);
}
__device__ __forceinline__ float bf2f(unsigned short u) {
    return __uint_as_float((unsigned)u << 16);
}

// ---------------------------------------------------------------------------
// CSR build (degree/scatter vectorized: 4 edges per thread via int4)
// ---------------------------------------------------------------------------
__global__ void degree_kernel(const int* __restrict__ ei, int* __restrict__ counts) {
    int e4 = (blockIdx.x * 256 + threadIdx.x) * 4;
    if (e4 < N_EDGES) {
        int4 d = *(const int4*)(ei + N_EDGES + e4);
        atomicAdd(&counts[d.x], 1);
        atomicAdd(&counts[d.y], 1);
        atomicAdd(&counts[d.z], 1);
        atomicAdd(&counts[d.w], 1);
    }
}

__global__ __launch_bounds__(256) void block_sum_kernel(const int* __restrict__ counts,
                                                        int* __restrict__ bsum) {
    int i = blockIdx.x * 256 + threadIdx.x;
    int v = (i < N_NODES) ? counts[i] : 0;
    #pragma unroll
    for (int o = 32; o >= 1; o >>= 1) v += __shfl_xor(v, o);
    __shared__ int ws[4];
    if ((threadIdx.x & 63) == 0) ws[threadIdx.x >> 6] = v;
    __syncthreads();
    if (threadIdx.x == 0) bsum[blockIdx.x] = ws[0] + ws[1] + ws[2] + ws[3];
}

__global__ __launch_bounds__(256) void scan_bsum_kernel(const int* __restrict__ bsum,
                                                        int* __restrict__ boff) {
    int t = threadIdx.x;
    int v = (t < SCAN_BLOCKS) ? bsum[t] : 0;
    int lane = t & 63, wid = t >> 6;
    int incl = v;
    #pragma unroll
    for (int o = 1; o < 64; o <<= 1) {
        int tv = __shfl_up(incl, o);
        if (lane >= o) incl += tv;
    }
    __shared__ int wsum[4];
    if (lane == 63) wsum[wid] = incl;
    __syncthreads();
    int add = 0;
    for (int w = 0; w < wid; w++) add += wsum[w];
    if (t < SCAN_BLOCKS) boff[t] = add + incl - v;   // exclusive
}

__global__ __launch_bounds__(256) void block_scan_kernel(const int* __restrict__ counts,
                                                         const int* __restrict__ boff,
                                                         int* __restrict__ offs,
                                                         int* __restrict__ cursor) {
    int i = blockIdx.x * 256 + threadIdx.x;
    int v = (i < N_NODES) ? counts[i] : 0;
    int lane = threadIdx.x & 63, wid = threadIdx.x >> 6;
    int incl = v;
    #pragma unroll
    for (int o = 1; o < 64; o <<= 1) {
        int tv = __shfl_up(incl, o);
        if (lane >= o) incl += tv;
    }
    __shared__ int wsum[4];
    if (lane == 63) wsum[wid] = incl;
    __syncthreads();
    int add = boff[blockIdx.x];
    for (int w = 0; w < wid; w++) add += wsum[w];
    if (i < N_NODES) {
        offs[i + 1] = add + incl;
        cursor[i]   = add + incl - v;
    }
    if (i == 0) offs[0] = 0;
}

__global__ void scatter_kernel(const int* __restrict__ ei, int* __restrict__ cursor,
                               int* __restrict__ csr) {
    int e4 = (blockIdx.x * 256 + threadIdx.x) * 4;
    if (e4 < N_EDGES) {
        int4 s = *(const int4*)(ei + e4);
        int4 d = *(const int4*)(ei + N_EDGES + e4);
        csr[atomicAdd(&cursor[d.x], 1)] = s.x;
        csr[atomicAdd(&cursor[d.y], 1)] = s.y;
        csr[atomicAdd(&cursor[d.z], 1)] = s.z;
        csr[atomicAdd(&cursor[d.w], 1)] = s.w;
    }
}

// ---------------------------------------------------------------------------
// Merged weight prep + pool init (one launch):
//  [0, 196608)          : pack qkv weights into MFMA frag layout (bf16)
//  [196608, 294912)     : pack fused [Wt;Wc], Wc = Ws@Wt computed on the fly
//  [294912, 295168)     : bc = bs@Wt + bt
//  [295168, 303360)     : zero psum/pmax
//  [303360, 303424)     : pcnt via binary search (gi sorted)
// ---------------------------------------------------------------------------
__global__ void weight_prep_kernel(
    const float* __restrict__ Wq, const float* __restrict__ Wk, const float* __restrict__ Wv,
    const float* __restrict__ Wsk, const float* __restrict__ Wt,
    const float* __restrict__ bs, const float* __restrict__ bt,
    const int* __restrict__ gi,
    unsigned short* __restrict__ outq, unsigned short* __restrict__ outf,
    float* __restrict__ bc,
    float* __restrict__ psum, unsigned* __restrict__ pmax, int* __restrict__ pcnt) {
    int idx = blockIdx.x * 256 + threadIdx.x;
    if (idx < 196608) {
        int j = idx & 7, lane = (idx >> 3) & 63, ct = (idx >> 9) & 15, ks = (idx >> 13) & 3;
        int m3 = idx >> 15;                          // 0..5
        int l = m3 / 3, m = m3 % 3;
        int k = ks * 32 + ((lane >> 4) * 8) + j;
        int n = ct * 16 + (lane & 15);
        const float* W = (m == 0) ? Wq : (m == 1) ? Wk : Wv;
        outq[idx] = f2bf(W[(size_t)l * 32768 + k * 256 + n]);
    } else if (idx < 294912) {
        int r = idx - 196608;
        int l = r / 49152, rr = r % 49152;
        int j = rr & 7, lane = (rr >> 3) & 63;
        int rest = rr >> 9;
        int ct = rest & 7, ks = rest >> 3;           // ks 0..11
        int k = ks * 32 + ((lane >> 4) * 8) + j;
        int n = ct * 16 + (lane & 15);
        float v;
        if (k < 256) {
            v = Wt[(size_t)l * 32768 + k * 128 + n];
        } else {
            const float* ws = Wsk + (size_t)l * 32768 + (size_t)(k - 256) * 256;
            const float* wt = Wt + (size_t)l * 32768;
            float s = 0.f;
            for (int kk = 0; kk < 256; kk++) s = fmaf(ws[kk], wt[kk * 128 + n], s);
            v = s;
        }
        outf[r] = f2bf(v);
    } else if (idx < 295168) {
        int t = idx - 294912;                        // 0..255
        int l = t >> 7, jj = t & 127;
        const float* wt = Wt + (size_t)l * 32768;
        float s = bt[l * 128 + jj];
        for (int kk = 0; kk < 256; kk++) s = fmaf(bs[l * 256 + kk], wt[kk * 128 + jj], s);
        bc[t] = s;
    } else if (idx < 303360) {
        int t = idx - 295168;                        // 0..8191
        psum[t] = 0.f;
        pmax[t] = 0u;
    } else if (idx < 303424) {
        int g = idx - 303360;                        // 0..63
        auto lb = [&](int target) {
            int lo = 0, hi = N_NODES;
            while (lo < hi) {
                int mid = (lo + hi) >> 1;
                if (gi[mid] < target) lo = mid + 1;
                else hi = mid;
            }
            return lo;
        };
        pcnt[g] = lb(g + 1) - lb(g);
    }
}

// ---------------------------------------------------------------------------
// Cooperative proj stage (R13 structure): 256-thread block, wave w owns 32
// rows whose bf16 x sit in its LDS tile slice. Weights streamed through a
// double-buffered 8 KB LDS chunk shared by all 4 waves.
// q -> bf16; k,v -> fp8 e4m3 into kv8 rows (uint 2c = k, 2c+1 = v).
// ---------------------------------------------------------------------------
__device__ __forceinline__ void proj_stream(
    const unsigned short* Tw, unsigned short* WB,
    const unsigned short* __restrict__ Wp,
    const float* __restrict__ b0, const float* __restrict__ b1, const float* __restrict__ b2,
    unsigned short* __restrict__ oq, unsigned* __restrict__ kv8,
    int rbase, int tid) {
    int lane = tid & 63, quad = lane >> 4, lr = lane & 15;
    int n0 = rbase + lr, n1 = rbase + 16 + lr;
    const float* bias[3] = {b0, b1, b2};

    bf16x8 pa0[4], pa1[4];
    #pragma unroll
    for (int ks = 0; ks < 4; ks++) {
        pa0[ks] = *(const bf16x8*)(Tw + lr * LROW + ks * 32 + quad * 8);
        pa1[ks] = *(const bf16x8*)(Tw + (16 + lr) * LROW + ks * 32 + quad * 8);
    }

    int f0 = tid, f1 = tid + 256;
    int ks0 = f0 >> 7, c20 = (f0 >> 6) & 1, ln0 = f0 & 63;
    int ks1 = f1 >> 7, c21 = (f1 >> 6) & 1, ln1 = f1 & 63;
    auto wload = [&](int c, uint4& r0, uint4& r1) {
        int mm = c >> 3, cp = c & 7;
        const unsigned short* base = Wp + mm * 32768;
        r0 = *(const uint4*)(base + (size_t)((ks0 * 16 + cp * 2 + c20) * 64 + ln0) * 8);
        r1 = *(const uint4*)(base + (size_t)((ks1 * 16 + cp * 2 + c21) * 64 + ln1) * 8);
    };

    auto epi = [&](int mm, int ct, const f32x4& e0, const f32x4& e1) {
        int ob = ct * 16 + quad * 4;
        float4 bb = *(const float4*)&bias[mm][ob];
        float v00 = e0[0] + bb.x, v01 = e0[1] + bb.y, v02 = e0[2] + bb.z, v03 = e0[3] + bb.w;
        float v10 = e1[0] + bb.x, v11 = e1[1] + bb.y, v12 = e1[2] + bb.z, v13 = e1[3] + bb.w;
        if (mm == 0) {
            ushort4 s0, s1;
            s0.x = f2bf(v00); s0.y = f2bf(v01); s0.z = f2bf(v02); s0.w = f2bf(v03);
            s1.x = f2bf(v10); s1.y = f2bf(v11); s1.z = f2bf(v12); s1.w = f2bf(v13);
            if (n0 < N_NODES) *(ushort4*)(oq + (size_t)n0 * 256 + ob) = s0;
            if (n1 < N_NODES) *(ushort4*)(oq + (size_t)n1 * 256 + ob) = s1;
        } else {
            int u0 = __builtin_amdgcn_cvt_pk_fp8_f32(v00, v01, 0, false);
            u0 = __builtin_amdgcn_cvt_pk_fp8_f32(v02, v03, u0, true);
            int u1 = __builtin_amdgcn_cvt_pk_fp8_f32(v10, v11, 0, false);
            u1 = __builtin_amdgcn_cvt_pk_fp8_f32(v12, v13, u1, true);
            int kvo = (ob >> 2) * 2 + (mm - 1);
            if (n0 < N_NODES) kv8[(size_t)n0 * 128 + kvo] = (unsigned)u0;
            if (n1 < N_NODES) kv8[(size_t)n1 * 128 + kvo] = (unsigned)u1;
        }
    };

    uint4 wr0, wr1;
    wload(0, wr0, wr1);
    ((uint4*)WB)[tid] = wr0;
    ((uint4*)WB)[tid + 256] = wr1;
    __syncthreads();

    for (int c = 0; c < 24; c++) {
        if (c < 23) wload(c + 1, wr0, wr1);
        const unsigned short* wb = WB + (c & 1) * 4096;
        f32x4 d00 = {0.f, 0.f, 0.f, 0.f}, d01 = {0.f, 0.f, 0.f, 0.f};
        f32x4 d10 = {0.f, 0.f, 0.f, 0.f}, d11 = {0.f, 0.f, 0.f, 0.f};
        #pragma unroll
        for (int ks = 0; ks < 4; ks++) {
            bf16x8 wf0 = *(const bf16x8*)(wb + ((ks * 2 + 0) * 64 + lane) * 8);
            bf16x8 wf1 = *(const bf16x8*)(wb + ((ks * 2 + 1) * 64 + lane) * 8);
            d00 = __builtin_amdgcn_mfma_f32_16x16x32_bf16(wf0, pa0[ks], d00, 0, 0, 0);
            d01 = __builtin_amdgcn_mfma_f32_16x16x32_bf16(wf0, pa1[ks], d01, 0, 0, 0);
            d10 = __builtin_amdgcn_mfma_f32_16x16x32_bf16(wf1, pa0[ks], d10, 0, 0, 0);
            d11 = __builtin_amdgcn_mfma_f32_16x16x32_bf16(wf1, pa1[ks], d11, 0, 0, 0);
        }
        int mm = c >> 3, ct0 = (c & 7) * 2;
        epi(mm, ct0, d00, d01);
        epi(mm, ct0 + 1, d10, d11);
        if (c < 23) {
            ((uint4*)(WB + ((c + 1) & 1) * 4096))[tid] = wr0;
            ((uint4*)(WB + ((c + 1) & 1) * 4096))[tid + 256] = wr1;
        }
        __syncthreads();
    }
}

// ---------------------------------------------------------------------------
// Layer-0 front (coop 128-row blocks): fp32 x -> bf16 xb (global) + LDS tile,
// then streamed qkv projection.
// ---------------------------------------------------------------------------
__global__ __launch_bounds__(256) void fproj_kernel(
    const float* __restrict__ xf, unsigned short* __restrict__ xb,
    const unsigned short* __restrict__ Wp,
    const float* __restrict__ b0, const float* __restrict__ b1, const float* __restrict__ b2,
    unsigned short* __restrict__ oq, unsigned* __restrict__ kv8) {
    __shared__ unsigned short T[128 * LROW];
    __shared__ unsigned short WB[8192];
    int tid = threadIdx.x;
    int w = tid >> 6, lane = tid & 63;
    int quad = lane >> 4, lr = lane & 15;
    int rbase = blockIdx.x * 128 + w * 32;
    unsigned short* Tw = T + w * 32 * LROW;

    #pragma unroll
    for (int s = 0; s < 2; s++) {
        int row = rbase + s * 16 + lr;
        if (row < N_NODES) {
            const float4* src = (const float4*)(xf + (size_t)row * 128 + quad * 32);
            ushort4* gdst = (ushort4*)(xb + (size_t)row * 128 + quad * 32);
            ushort4* ldst = (ushort4*)(Tw + (s * 16 + lr) * LROW + quad * 32);
            #pragma unroll
            for (int i = 0; i < 8; i++) {
                float4 v = src[i];
                ushort4 o;
                o.x = f2bf(v.x); o.y = f2bf(v.y); o.z = f2bf(v.z); o.w = f2bf(v.w);
                gdst[i] = o;
                ldst[i] = o;
            }
        }
    }
    proj_stream(Tw, WB, Wp, b0, b1, b2, oq, kv8, rbase, tid);
}

// ---------------------------------------------------------------------------
// Fused output linear (+ next layer's qkv projection when do_proj), coop
// 128-row blocks: x_next = relu([h|x] @ [Wt;Wc] + bc), weights streamed by ks
// through the LDS double buffer (12 chunks), A prefetched 1 ahead.
// ---------------------------------------------------------------------------
__global__ __launch_bounds__(256) void outproj_kernel(
    const unsigned short* __restrict__ hb, const unsigned short* __restrict__ xbin,
    const unsigned short* __restrict__ Wfp, const float* __restrict__ bc,
    unsigned short* __restrict__ xbout,
    const unsigned short* __restrict__ Wp,
    const float* __restrict__ b0, const float* __restrict__ b1, const float* __restrict__ b2,
    unsigned short* __restrict__ oq, unsigned* __restrict__ kv8, int do_proj) {
    __shared__ unsigned short T[128 * LROW];
    __shared__ unsigned short WB[8192];
    int tid = threadIdx.x;
    int w = tid >> 6, lane = tid & 63;
    int quad = lane >> 4, lr = lane & 15;
    int rbase = blockIdx.x * 128 + w * 32;
    int n0 = rbase + lr, n1 = rbase + 16 + lr;
    int n0c = min(n0, N_NODES - 1), n1c = min(n1, N_NODES - 1);
    unsigned short* Tw = T + w * 32 * LROW;

    auto load_a = [&](int ks, bf16x8& x0, bf16x8& x1) {
        if (ks < 8) {
            x0 = *(const bf16x8*)(hb + (size_t)n0c * 256 + ks * 32 + quad * 8);
            x1 = *(const bf16x8*)(hb + (size_t)n1c * 256 + ks * 32 + quad * 8);
        } else {
            x0 = *(const bf16x8*)(xbin + (size_t)n0c * 128 + (ks - 8) * 32 + quad * 8);
            x1 = *(const bf16x8*)(xbin + (size_t)n1c * 128 + (ks - 8) * 32 + quad * 8);
        }
    };

    f32x4 acc[8][2];
    #pragma unroll
    for (int ct = 0; ct < 8; ct++) {
        acc[ct][0] = (f32x4){0.f, 0.f, 0.f, 0.f};
        acc[ct][1] = (f32x4){0.f, 0.f, 0.f, 0.f};
    }

    uint4 wr0 = ((const uint4*)Wfp)[tid];
    uint4 wr1 = ((const uint4*)Wfp)[tid + 256];
    ((uint4*)WB)[tid] = wr0;
    ((uint4*)WB)[tid + 256] = wr1;
    bf16x8 a0c, a1c, a0n, a1n;
    load_a(0, a0c, a1c);
    __syncthreads();

    for (int ks = 0; ks < 12; ks++) {
        if (ks < 11) {
            wr0 = ((const uint4*)(Wfp + (size_t)(ks + 1) * 4096))[tid];
            wr1 = ((const uint4*)(Wfp + (size_t)(ks + 1) * 4096))[tid + 256];
            load_a(ks + 1, a0n, a1n);
        }
        const unsigned short* wb = WB + (ks & 1) * 4096;
        #pragma unroll
        for (int ct = 0; ct < 8; ct++) {
            bf16x8 wf = *(const bf16x8*)(wb + (ct * 64 + lane) * 8);
            acc[ct][0] = __builtin_amdgcn_mfma_f32_16x16x32_bf16(wf, a0c, acc[ct][0], 0, 0, 0);
            acc[ct][1] = __builtin_amdgcn_mfma_f32_16x16x32_bf16(wf, a1c, acc[ct][1], 0, 0, 0);
        }
        if (ks < 11) {
            ((uint4*)(WB + ((ks + 1) & 1) * 4096))[tid] = wr0;
            ((uint4*)(WB + ((ks + 1) & 1) * 4096))[tid + 256] = wr1;
            a0c = a0n;
            a1c = a1n;
        }
        __syncthreads();
    }

    #pragma unroll
    for (int ct = 0; ct < 8; ct++) {
        int ob = ct * 16 + quad * 4;
        float4 bb = *(const float4*)&bc[ob];
        ushort4 s0, s1;
        s0.x = f2bf(fmaxf(acc[ct][0][0] + bb.x, 0.f));
        s0.y = f2bf(fmaxf(acc[ct][0][1] + bb.y, 0.f));
        s0.z = f2bf(fmaxf(acc[ct][0][2] + bb.z, 0.f));
        s0.w = f2bf(fmaxf(acc[ct][0][3] + bb.w, 0.f));
        s1.x = f2bf(fmaxf(acc[ct][1][0] + bb.x, 0.f));
        s1.y = f2bf(fmaxf(acc[ct][1][1] + bb.y, 0.f));
        s1.z = f2bf(fmaxf(acc[ct][1][2] + bb.z, 0.f));
        s1.w = f2bf(fmaxf(acc[ct][1][3] + bb.w, 0.f));
        if (n0 < N_NODES) *(ushort4*)(xbout + (size_t)n0 * 128 + ob) = s0;
        if (n1 < N_NODES) *(ushort4*)(xbout + (size_t)n1 * 128 + ob) = s1;
        *(ushort4*)(Tw + lr * LROW + ob) = s0;
        *(ushort4*)(Tw + (16 + lr) * LROW + ob) = s1;
    }

    if (do_proj) {
        proj_stream(Tw, WB, Wp, b0, b1, b2, oq, kv8, rbase, tid);
    }
}

// ---------------------------------------------------------------------------
// Attention: 256-thread blocks, one dst/wave, unroll 8. Single pass, no
// max-subtraction (|logit|<~3, exp-safe; softmax shift-invariant).
// k,v both fp8 e4m3: lane reads ONE uint2 (8B) = [k-pack | v-pack] per edge.
// ---------------------------------------------------------------------------
__global__ __launch_bounds__(256) void attn_kernel(
    const unsigned short* __restrict__ q, const unsigned* __restrict__ kv8,
    const int* __restrict__ offs, const int* __restrict__ csr,
    unsigned short* __restrict__ hout) {
    const float SCALE = 0.08838834764831845f;  // 1/sqrt(128)
    int w = threadIdx.x >> 6, lane = threadIdx.x & 63;
    int n = blockIdx.x * 4 + w;                // 12500*4 = 50000 exactly
    ushort4 qu = ((const ushort4*)(q + (size_t)n * 256))[lane];
    float4 q4 = make_float4(bf2f(qu.x), bf2f(qu.y), bf2f(qu.z), bf2f(qu.w));
    int beg = offs[n], end = offs[n + 1];

    float4 acc = make_float4(0.f, 0.f, 0.f, 0.f);
    float d = 0.f;

    int j = beg;
    for (; j + 8 <= end; j += 8) {
        uint2 c[8];
        #pragma unroll
        for (int u = 0; u < 8; u++) {
            int s = csr[j + u];
            c[u] = ((const uint2*)(kv8 + (size_t)s * 128))[lane];
        }
        float p[8];
        #pragma unroll
        for (int u = 0; u < 8; u++) {
            f32x2 lo = __builtin_amdgcn_cvt_pk_f32_fp8((int)c[u].x, false);
            f32x2 hi = __builtin_amdgcn_cvt_pk_f32_fp8((int)c[u].x, true);
            p[u] = q4.x * lo.x + q4.y * lo.y + q4.z * hi.x + q4.w * hi.y;
        }
        #pragma unroll
        for (int o = 16; o >= 1; o >>= 1) {
            #pragma unroll
            for (int u = 0; u < 8; u++) p[u] += __shfl_xor(p[u], o);
        }
        #pragma unroll
        for (int u = 0; u < 8; u++) {
            float e = __expf(p[u] * SCALE);
            d += e;
            f32x2 vlo = __builtin_amdgcn_cvt_pk_f32_fp8((int)c[u].y, false);
            f32x2 vhi = __builtin_amdgcn_cvt_pk_f32_fp8((int)c[u].y, true);
            acc.x = fmaf(e, vlo.x, acc.x);
            acc.y = fmaf(e, vlo.y, acc.y);
            acc.z = fmaf(e, vhi.x, acc.z);
            acc.w = fmaf(e, vhi.y, acc.w);
        }
    }
    for (; j < end; j++) {
        int s = csr[j];
        uint2 c = ((const uint2*)(kv8 + (size_t)s * 128))[lane];
        f32x2 lo = __builtin_amdgcn_cvt_pk_f32_fp8((int)c.x, false);
        f32x2 hi = __builtin_amdgcn_cvt_pk_f32_fp8((int)c.x, true);
        float p = q4.x * lo.x + q4.y * lo.y + q4.z * hi.x + q4.w * hi.y;
        #pragma unroll
        for (int o = 16; o >= 1; o >>= 1) p += __shfl_xor(p, o);
        float e = __expf(p * SCALE);
        d += e;
        f32x2 vlo = __builtin_amdgcn_cvt_pk_f32_fp8((int)c.y, false);
        f32x2 vhi = __builtin_amdgcn_cvt_pk_f32_fp8((int)c.y, true);
        acc.x = fmaf(e, vlo.x, acc.x);
        acc.y = fmaf(e, vlo.y, acc.y);
        acc.z = fmaf(e, vhi.x, acc.z);
        acc.w = fmaf(e, vhi.y, acc.w);
    }

    float inv = 1.f / (d + 1e-16f);
    ushort4 hv;
    hv.x = f2bf(acc.x * inv);
    hv.y = f2bf(acc.y * inv);
    hv.z = f2bf(acc.z * inv);
    hv.w = f2bf(acc.w * inv);
    ((ushort4*)(hout + (size_t)n * 256))[lane] = hv;
}

// ---------------------------------------------------------------------------
// Pooling from bf16 x, ushort4-vectorized, run-compressed (gi sorted).
// relu output >= 0 => uint atomicMax order-correct, 0 is the identity.
// ---------------------------------------------------------------------------
__global__ __launch_bounds__(256) void pool_accum_kernel(
    const unsigned short* __restrict__ xb, const int* __restrict__ gi,
    float* __restrict__ psum, unsigned* __restrict__ pmax) {
    int n0 = blockIdx.x * 128;
    int c4 = (threadIdx.x & 31) * 4;        // 4 consecutive cols
    int phase = threadIdx.x >> 5;           // 0..7
    int first = n0 + phase;
    if (first >= N_NODES) return;
    float s0 = 0.f, s1 = 0.f, s2 = 0.f, s3 = 0.f;
    float m0 = 0.f, m1 = 0.f, m2 = 0.f, m3 = 0.f;
    int cur_g = gi[first];
    for (int r = phase; r < 128; r += 8) {
        int n = n0 + r;
        if (n >= N_NODES) break;
        int g = gi[n];
        if (g != cur_g) {
            float* ps = &psum[cur_g * 128 + c4];
            unsigned* pm = &pmax[cur_g * 128 + c4];
            atomicAdd(ps + 0, s0); atomicAdd(ps + 1, s1);
            atomicAdd(ps + 2, s2); atomicAdd(ps + 3, s3);
            atomicMax(pm + 0, __float_as_uint(m0)); atomicMax(pm + 1, __float_as_uint(m1));
            atomicMax(pm + 2, __float_as_uint(m2)); atomicMax(pm + 3, __float_as_uint(m3));
            s0 = s1 = s2 = s3 = 0.f;
            m0 = m1 = m2 = m3 = 0.f;
            cur_g = g;
        }
        ushort4 u = *(const ushort4*)(xb + (size_t)n * 128 + c4);
        float v0 = bf2f(u.x), v1 = bf2f(u.y), v2 = bf2f(u.z), v3 = bf2f(u.w);
        s0 += v0; s1 += v1; s2 += v2; s3 += v3;
        m0 = fmaxf(m0, v0); m1 = fmaxf(m1, v1);
        m2 = fmaxf(m2, v2); m3 = fmaxf(m3, v3);
    }
    float* ps = &psum[cur_g * 128 + c4];
    unsigned* pm = &pmax[cur_g * 128 + c4];
    atomicAdd(ps + 0, s0); atomicAdd(ps + 1, s1);
    atomicAdd(ps + 2, s2); atomicAdd(ps + 3, s3);
    atomicMax(pm + 0, __float_as_uint(m0)); atomicMax(pm + 1, __float_as_uint(m1));
    atomicMax(pm + 2, __float_as_uint(m2)); atomicMax(pm + 3, __float_as_uint(m3));
}

__global__ void pool_final_kernel(const float* __restrict__ psum, const unsigned* __restrict__ pmax,
                                  const int* __restrict__ pcnt, float* __restrict__ out) {
    int idx = blockIdx.x * 256 + threadIdx.x;
    if (idx >= NGRAPH * 384) return;
    int g = idx / 384, c = idx % 384;
    float r;
    if (c < 128)       r = __uint_as_float(pmax[g * 128 + c]);
    else if (c < 256)  r = psum[g * 128 + (c - 128)] / fmaxf((float)pcnt[g], 1.f);
    else               r = psum[g * 128 + (c - 256)];
    out[idx] = r;
}

// ---------------------------------------------------------------------------
extern "C" void kernel_launch(void* const* d_in, const int* in_sizes, int n_in,
                              void* d_out, int out_size, void* d_ws, size_t ws_size,
                              hipStream_t stream) {
    const float* x   = (const float*)d_in[0];
    const int*   ei  = (const int*)d_in[1];
    const int*   gi  = (const int*)d_in[2];
    const float* Wq  = (const float*)d_in[3];
    const float* bq  = (const float*)d_in[4];
    const float* Wk  = (const float*)d_in[5];
    const float* bk  = (const float*)d_in[6];
    const float* Wv  = (const float*)d_in[7];
    const float* bv  = (const float*)d_in[8];
    const float* Wsk = (const float*)d_in[9];
    const float* bsk = (const float*)d_in[10];
    const float* Wt  = (const float*)d_in[11];
    const float* bt  = (const float*)d_in[12];
    float* out = (float*)d_out;

    char* p = (char*)d_ws;
    auto take = [&](size_t bytes) -> char* {
        char* r = p;
        p += (bytes + 255) & ~(size_t)255;
        return r;
    };
    unsigned short* qbuf   = (unsigned short*)take((size_t)N_NODES * 256 * 2);  // q bf16
    unsigned*       kv8buf = (unsigned*)take((size_t)N_NODES * 128 * 4);        // k|v fp8 packed
    unsigned short* xb     = (unsigned short*)take((size_t)N_NODES * 128 * 2);  // x0 bf16 / final x
    unsigned short* xb2    = (unsigned short*)take((size_t)N_NODES * 128 * 2);  // x1 bf16
    unsigned short* hb     = (unsigned short*)take((size_t)N_NODES * 256 * 2);  // attn out bf16
    unsigned short* Wqkvp  = (unsigned short*)take((size_t)196608 * 2);         // packed qkv
    unsigned short* Wfp    = (unsigned short*)take((size_t)98304 * 2);          // packed [Wt;Wc]
    float*          bc     = (float*)take(2 * 128 * 4);
    int*            counts = (int*)take((size_t)N_NODES * 4);
    int*            offs   = (int*)take((size_t)(N_NODES + 1) * 4);
    int*            cursor = (int*)take((size_t)N_NODES * 4);
    int*            csr    = (int*)take((size_t)N_EDGES * 4);
    int*            bsum   = (int*)take((size_t)SCAN_BLOCKS * 4);
    int*            boff   = (int*)take((size_t)SCAN_BLOCKS * 4);
    float*          psum   = (float*)take(NGRAPH * 128 * 4);
    unsigned*       pmax   = (unsigned*)take(NGRAPH * 128 * 4);
    int*            pcnt   = (int*)take(NGRAPH * 4);

    const int E4B = (N_EDGES / 4 + 255) / 256;     // 782  (4 edges/thread)
    const int GB  = (N_NODES + 127) / 128;         // 391  (coop GEMM / pooling blocks)
    const int AB  = (N_NODES + 3) / 4;             // 12500 (attn blocks, 4 dst/block)
    const int WPB = (303424 + 255) / 256;          // 1186 (merged weight prep + pool init)

    // ---- CSR build ----
    hipMemsetAsync(counts, 0, (size_t)N_NODES * 4, stream);
    degree_kernel<<<E4B, 256, 0, stream>>>(ei, counts);
    block_sum_kernel<<<SCAN_BLOCKS, 256, 0, stream>>>(counts, bsum);
    scan_bsum_kernel<<<1, 256, 0, stream>>>(bsum, boff);
    block_scan_kernel<<<SCAN_BLOCKS, 256, 0, stream>>>(counts, boff, offs, cursor);
    scatter_kernel<<<E4B, 256, 0, stream>>>(ei, cursor, csr);

    // ---- weight prep + pool init (single launch) ----
    weight_prep_kernel<<<WPB, 256, 0, stream>>>(Wq, Wk, Wv, Wsk, Wt, bsk, bt, gi,
                                                Wqkvp, Wfp, bc, psum, pmax, pcnt);

    // ---- layer 0 ----
    fproj_kernel<<<GB, 256, 0, stream>>>(x, xb, Wqkvp, bq, bk, bv, qbuf, kv8buf);
    attn_kernel<<<AB, 256, 0, stream>>>(qbuf, kv8buf, offs, csr, hb);
    // out(L0) fused with proj(L1)
    outproj_kernel<<<GB, 256, 0, stream>>>(hb, xb, Wfp, bc, xb2,
                                           Wqkvp + 98304, bq + 256, bk + 256, bv + 256,
                                           qbuf, kv8buf, 1);
    // ---- layer 1 ----
    attn_kernel<<<AB, 256, 0, stream>>>(qbuf, kv8buf, offs, csr, hb);
    outproj_kernel<<<GB, 256, 0, stream>>>(hb, xb2, Wfp + 49152, bc + 128, xb,
                                           Wqkvp, bq, bk, bv, qbuf, kv8buf, 0);

    // ---- pooling ----
    pool_accum_kernel<<<GB, 256, 0, stream>>>(xb, gi, psum, pmax);
    pool_final_kernel<<<(NGRAPH * 384 + 255) / 256, 256, 0, stream>>>(psum, pmax, pcnt, out);
}